// Round 8
// baseline (184.163 us; speedup 1.0000x reference)
//
#include <hip/hip_runtime.h>
#include <math.h>

typedef unsigned short u16;
typedef u16 u16x4 __attribute__((ext_vector_type(4)));
typedef u16 u16x8 __attribute__((ext_vector_type(8)));
typedef float f32x4 __attribute__((ext_vector_type(4)));
typedef float f32x16 __attribute__((ext_vector_type(16)));
typedef __bf16 bf16x8 __attribute__((ext_vector_type(8)));

#define KC 8
#define K2L 2304  // 256*9
#define NBLK 256

__device__ __forceinline__ u16 f2bf_rne(float f) {
  unsigned u = __float_as_uint(f);
  u += 0x7FFFu + ((u >> 16) & 1u);
  return (u16)(u >> 16);
}
__device__ __forceinline__ float bf2f(u16 h) {
  return __uint_as_float(((unsigned)h) << 16);
}

// async global->LDS, 16B/lane; LDS dest is the WAVE-UNIFORM base (HW adds lane*16)
__device__ __forceinline__ void gload16(const u16* g, u16* l) {
  __builtin_amdgcn_global_load_lds(
      (const __attribute__((address_space(1))) unsigned*)g,
      (__attribute__((address_space(3))) unsigned*)l, 16, 0, 0);
}

template <int N>
__device__ __forceinline__ void vmwait() {
  if constexpr (N == 0)       asm volatile("s_waitcnt vmcnt(0)" ::: "memory");
  else if constexpr (N == 8)  asm volatile("s_waitcnt vmcnt(8)" ::: "memory");
  else if constexpr (N == 16) asm volatile("s_waitcnt vmcnt(16)" ::: "memory");
  else static_assert(N == 0, "unsupported vmcnt literal");
}

// ---- device-scope grid barrier (sense-reversal; state in d_ws, zeroed per launch) ----
struct BarSt { int cnt; int gen; };
__device__ __forceinline__ void grid_barrier(BarSt* bs) {
  __syncthreads();
  if (threadIdx.x == 0) {
    int g = __hip_atomic_load(&bs->gen, __ATOMIC_RELAXED, __HIP_MEMORY_SCOPE_AGENT);
    int prev = __hip_atomic_fetch_add(&bs->cnt, 1, __ATOMIC_ACQ_REL, __HIP_MEMORY_SCOPE_AGENT);
    if (prev == NBLK - 1) {
      __hip_atomic_store(&bs->cnt, 0, __ATOMIC_RELAXED, __HIP_MEMORY_SCOPE_AGENT);
      __hip_atomic_store(&bs->gen, g + 1, __ATOMIC_RELEASE, __HIP_MEMORY_SCOPE_AGENT);
    } else {
      while (__hip_atomic_load(&bs->gen, __ATOMIC_ACQUIRE, __HIP_MEMORY_SCOPE_AGENT) == g) {}
    }
  }
  __syncthreads();
}

// ---- prep helpers ----
__device__ __forceinline__ void split4(const float* X, u16* hi, u16* lo, int i) {
  f32x4 v = ((const f32x4*)X)[i];
  u16x4 h, l;
#pragma unroll
  for (int c = 0; c < 4; ++c) {
    u16 hb = f2bf_rne(v[c]);
    h[c] = hb;
    l[c] = f2bf_rne(v[c] - bf2f(hb));
  }
  ((u16x4*)hi)[i] = h;
  ((u16x4*)lo)[i] = l;
}
__device__ __forceinline__ void wc_one(const float* coef, const float* sb, const float* sp,
                                       const float* mask, u16* W, int N, int idx) {
  int o = idx / K2L;
  int r = idx - o * K2L;
  int i = r / 9;
  int c = r - i * 9;
  int io = i * N + o;
  float m = mask[io];
  float v = (c == 0) ? m * sb[io] : m * sp[io] * coef[(size_t)io * KC + (c - 1)];
  W[idx] = f2bf_rne(v);
}

// ---- spline tables + divide-free expand ----
struct Spl {
  float g[12];
  float d1[11], d2[10], d3[9];
};
__device__ __forceinline__ void spl_init(const float* __restrict__ grid, Spl& sp) {
#pragma unroll
  for (int j = 0; j < 12; ++j) sp.g[j] = grid[j];
#pragma unroll
  for (int j = 0; j < 11; ++j) sp.d1[j] = 1.0f / (sp.g[j + 1] - sp.g[j]);
#pragma unroll
  for (int j = 0; j < 10; ++j) sp.d2[j] = 1.0f / (sp.g[j + 2] - sp.g[j]);
#pragma unroll
  for (int j = 0; j < 9; ++j) sp.d3[j] = 1.0f / (sp.g[j + 3] - sp.g[j]);
}
__device__ __forceinline__ void expand_one(float v, const Spl& sp, u16* dst) {
  float Bv[11];
#pragma unroll
  for (int j = 0; j < 11; ++j) Bv[j] = (v >= sp.g[j] && v < sp.g[j + 1]) ? 1.0f : 0.0f;
#pragma unroll
  for (int j = 0; j < 10; ++j)
    Bv[j] = (v - sp.g[j]) * sp.d1[j] * Bv[j] + (sp.g[j + 2] - v) * sp.d1[j + 1] * Bv[j + 1];
#pragma unroll
  for (int j = 0; j < 9; ++j)
    Bv[j] = (v - sp.g[j]) * sp.d2[j] * Bv[j] + (sp.g[j + 3] - v) * sp.d2[j + 1] * Bv[j + 1];
#pragma unroll
  for (int j = 0; j < 8; ++j)
    Bv[j] = (v - sp.g[j]) * sp.d3[j] * Bv[j] + (sp.g[j + 4] - v) * sp.d3[j + 1] * Bv[j + 1];
  dst[0] = f2bf_rne(v / (1.0f + __expf(-v)));  // silu
#pragma unroll
  for (int k = 0; k < 8; ++k) dst[1 + k] = f2bf_rne(Bv[k]);
}

// ---- one GEMM phase (R6-proven core): BM=BN=64, 4 waves, wave-tile 32x32,
// BK=128, 4-buf ring, depth-2 prefetch, counted vmcnt, 1 s_barrier/step.
// NREG==3: K'=3*K regions hh/hl/lh (split-precision bf16x3, K=1024).
// EXPAND: bias+spline epilogue -> bf16 F[M][N*9]; else f32 C[M][N].
template <int NREG, bool EXPAND>
__device__ void gemm_phase(const u16* __restrict__ A0, const u16* __restrict__ A1,
                           const u16* __restrict__ B0, const u16* __restrict__ B1,
                           const float* __restrict__ bias, const float* __restrict__ grid,
                           void* __restrict__ outv, int M, int N, int K, int nsteps,
                           u16* smu, int bid) {
  constexpr int ASZ = 64 * 128;  // u16
  constexpr int BUF_U16 = 2 * ASZ;

  const int tid = threadIdx.x;
  const int lane = tid & 63;
  const int wid = tid >> 6;

  // XCD-aware swizzle (tile counts are multiples of 8)
  const int nb = N >> 6;
  const int nwg = (M >> 6) * nb;
  const int swz = (bid & 7) * (nwg >> 3) + (bid >> 3);
  const int tm = (swz / nb) << 6;
  const int tn = (swz % nb) << 6;

  const size_t gAoff = (size_t)tm * K;
  const size_t gBoff = (size_t)tn * K;

  // chunk c: row=c>>4, slot=c&15; slot sources logical k-group slot^(row&15)
  auto srcOff = [&](int c) -> size_t {
    int r = c >> 4, sl = c & 15;
    return (size_t)r * K + (size_t)(((sl ^ (r & 15)) & 15) << 3);
  };
  size_t aSrc[4], bSrc[4];
#pragma unroll
  for (int c = 0; c < 4; ++c) aSrc[c] = srcOff(tid + c * 256);
#pragma unroll
  for (int c = 0; c < 4; ++c) bSrc[c] = srcOff(tid + c * 256);

  const int wm = (wid >> 1) * 32;
  const int wn = (wid & 1) * 32;
  const int lr = lane & 31;
  const int khf = lane >> 5;

  // swizzled LDS read offsets: row*128 + ((ks*2+khf)^(row&15))*8
  int offA[8], offB[8];
#pragma unroll
  for (int ks = 0; ks < 8; ++ks) {
    int rowA = wm + lr;
    int rowB = wn + lr;
    offA[ks] = rowA * 128 + ((((ks * 2 + khf) ^ (rowA & 15)) & 15) << 3);
    offB[ks] = rowB * 128 + ((((ks * 2 + khf) ^ (rowB & 15)) & 15) << 3);
  }

  auto stage = [&](int buf, int step) {
    int kk;
    const u16 *Ab, *Bb;
    if constexpr (NREG == 3) {
      int reg = step >> 3;  // K==1024 -> 8 BK-128 steps per region
      kk = (step & 7) << 7;
      Ab = (reg == 2) ? A1 : A0;
      Bb = (reg == 1) ? B1 : B0;
    } else {
      kk = step << 7;
      Ab = A0;
      Bb = B0;
    }
    u16* sb = smu + buf * BUF_U16;
#pragma unroll
    for (int c = 0; c < 4; ++c)
      gload16(Ab + gAoff + aSrc[c] + kk, sb + (c * 256 + wid * 64) * 8);
#pragma unroll
    for (int c = 0; c < 4; ++c)
      gload16(Bb + gBoff + bSrc[c] + kk, sb + ASZ + (c * 256 + wid * 64) * 8);
  };

  f32x16 acc0 = {}, acc1 = {};
  stage(0, 0);
  stage(1, 1);
  for (int i = 0; i < nsteps; ++i) {
    if (i + 2 < nsteps) {
      stage((i + 2) & 3, i + 2);
      vmwait<16>();  // my loads for buf[i&3] landed; 2 stages (2x8) in flight
    } else if (i + 1 < nsteps) {
      vmwait<8>();
    } else {
      vmwait<0>();
    }
    __builtin_amdgcn_sched_barrier(0);
    __builtin_amdgcn_s_barrier();  // everyone's loads for buf[i&3] landed;
                                   // also fences reads of buf[(i+2)&3] (iter i-2)
    __builtin_amdgcn_sched_barrier(0);

    const u16* sb = smu + (i & 3) * BUF_U16;
    bf16x8 af[8], bfr[8];
#pragma unroll
    for (int ks = 0; ks < 8; ++ks) {
      af[ks] = *(const bf16x8*)(sb + offA[ks]);
      bfr[ks] = *(const bf16x8*)(sb + ASZ + offB[ks]);
    }
#pragma unroll
    for (int ks = 0; ks < 8; ++ks) {
      f32x16& ac = (ks & 1) ? acc1 : acc0;
      ac = __builtin_amdgcn_mfma_f32_32x32x16_bf16(af[ks], bfr[ks], ac, 0, 0, 0);
    }
  }
  f32x16 accv = acc0 + acc1;

  // C/D layout (m74/m101): col = lane&31, row = (r&3) + 8*(r>>2) + 4*(lane>>5)
  const int col = lr;
  const int rbase = 4 * khf;
  if constexpr (EXPAND) {
    Spl sp;
    spl_init(grid, sp);
    __syncthreads();  // stage LDS reusable for F tile
    u16* Fl = smu;
    const float bv = bias ? bias[tn + wn + col] : 0.0f;
#pragma unroll
    for (int r = 0; r < 16; ++r) {
      int row = wm + rbase + (r & 3) + 8 * (r >> 2);
      expand_one(accv[r] + bv, sp, Fl + (size_t)row * (64 * 9) + (wn + col) * 9);
    }
    __syncthreads();
    // coalesced copy-out: 64 x 576 bf16 in 16B chunks
    u16* Fout = (u16*)outv;
    constexpr int RB = 64 * 9 / 8;  // 72 chunks/row
    constexpr int CH = 64 * RB;
    const size_t fstride = (size_t)N * 9;
#pragma unroll 2
    for (int ch = tid; ch < CH; ch += 256) {
      int r = ch / RB, o = ch - r * RB;
      *(u16x8*)(Fout + (size_t)(tm + r) * fstride + (size_t)tn * 9 + o * 8) =
          *(const u16x8*)(Fl + (size_t)ch * 8);
    }
  } else {
    float* Cp = (float*)outv;
#pragma unroll
    for (int r = 0; r < 16; ++r) {
      int row = tm + wm + rbase + (r & 3) + 8 * (r >> 2);
      Cp[(size_t)row * N + tn + wn + col] = accv[r];
    }
  }
}

// ---- the whole network in one persistent kernel ----
__global__ __launch_bounds__(256) void kan_all(
    const float* __restrict__ x, const float* __restrict__ W1, const float* __restrict__ b1,
    const float* __restrict__ grid1, const float* __restrict__ coef1,
    const float* __restrict__ sb1, const float* __restrict__ sp1, const float* __restrict__ mask1,
    const float* __restrict__ grid2, const float* __restrict__ coef2,
    const float* __restrict__ sb2, const float* __restrict__ sp2, const float* __restrict__ mask2,
    u16* __restrict__ xs_hi, u16* __restrict__ xs_lo,
    u16* __restrict__ w1_hi, u16* __restrict__ w1_lo,
    u16* __restrict__ wc1, u16* __restrict__ wc2,
    u16* __restrict__ F1, u16* __restrict__ F2,
    float* __restrict__ outp, BarSt* bs) {
  __shared__ __align__(16) u16 smu[4 * 2 * 64 * 128];  // 128 KB (4-buf ring)
  const int bid = blockIdx.x;
  const int tid = threadIdx.x;

  // phase 0: prep (grid-strided over 7808 unit-blocks of 256)
  for (int u = bid; u < 7808; u += NBLK) {
    if (u < 4096) {
      split4(x, xs_hi, xs_lo, u * 256 + tid);
    } else if (u < 4352) {
      split4(W1, w1_hi, w1_lo, (u - 4096) * 256 + tid);
    } else if (u < 6656) {
      wc_one(coef1, sb1, sp1, mask1, wc1, 256, (u - 4352) * 256 + tid);
    } else {
      wc_one(coef2, sb2, sp2, mask2, wc2, 128, (u - 6656) * 256 + tid);
    }
  }
  grid_barrier(bs);

  // phase 1: F1 = expand(x @ W1^T + b1); bf16x3 as K'=3072; 24 steps; 256 tiles
  gemm_phase<3, true>(xs_hi, xs_lo, w1_hi, w1_lo, b1, grid1, F1, 4096, 256, 1024, 24, smu, bid);
  grid_barrier(bs);

  // phase 2: F2 = expand(F1 @ Wc1^T); K=2304; 18 steps; 256 tiles
  gemm_phase<1, true>(F1, nullptr, wc1, nullptr, nullptr, grid2, F2, 4096, 256, 2304, 18, smu, bid);
  grid_barrier(bs);

  // phase 3: out = F2 @ Wc2^T; K=2304, N=128; 18 steps; 128 tiles
  if (bid < 128)
    gemm_phase<1, false>(F2, nullptr, wc2, nullptr, nullptr, nullptr, outp, 4096, 128, 2304, 18, smu, bid);
}

extern "C" void kernel_launch(void* const* d_in, const int* in_sizes, int n_in,
                              void* d_out, int out_size, void* d_ws, size_t ws_size,
                              hipStream_t stream) {
  (void)in_sizes; (void)n_in; (void)out_size; (void)ws_size;
  const float* x     = (const float*)d_in[0];
  const float* W1    = (const float*)d_in[1];
  const float* b1    = (const float*)d_in[2];
  const float* grid1 = (const float*)d_in[3];
  const float* coef1 = (const float*)d_in[4];
  const float* sb1   = (const float*)d_in[5];
  const float* sp1   = (const float*)d_in[6];
  const float* mask1 = (const float*)d_in[7];
  const float* grid2 = (const float*)d_in[8];
  const float* coef2 = (const float*)d_in[9];
  const float* sb2   = (const float*)d_in[10];
  const float* sp2   = (const float*)d_in[11];
  const float* mask2 = (const float*)d_in[12];
  float* outp = (float*)d_out;

  char* ws = (char*)d_ws;
  size_t off = 0;
  auto alloc = [&](size_t bytes) {
    char* p = ws + off;
    off += (bytes + 255) & ~(size_t)255;
    return (void*)p;
  };
  BarSt* bs   = (BarSt*)alloc(256);
  u16* xs_hi  = (u16*)alloc((size_t)4096 * 1024 * 2);
  u16* xs_lo  = (u16*)alloc((size_t)4096 * 1024 * 2);
  u16* w1_hi  = (u16*)alloc((size_t)256 * 1024 * 2);
  u16* w1_lo  = (u16*)alloc((size_t)256 * 1024 * 2);
  u16* wc1    = (u16*)alloc((size_t)256 * K2L * 2);
  u16* wc2    = (u16*)alloc((size_t)128 * K2L * 2);
  u16* F1     = (u16*)alloc((size_t)4096 * K2L * 2);
  u16* F2     = (u16*)alloc((size_t)4096 * K2L * 2);

  hipMemsetAsync(bs, 0, 256, stream);  // zero barrier state every launch (replay-safe)
  kan_all<<<NBLK, 256, 0, stream>>>(x, W1, b1, grid1, coef1, sb1, sp1, mask1,
                                    grid2, coef2, sb2, sp2, mask2,
                                    xs_hi, xs_lo, w1_hi, w1_lo, wc1, wc2,
                                    F1, F2, outp, bs);
}

// Round 9
// 150.747 us; speedup vs baseline: 1.2217x; 1.2217x over previous
//
#include <hip/hip_runtime.h>
#include <math.h>

typedef unsigned short u16;
typedef u16 u16x4 __attribute__((ext_vector_type(4)));
typedef u16 u16x8 __attribute__((ext_vector_type(8)));
typedef float f32x4 __attribute__((ext_vector_type(4)));
typedef float f32x16 __attribute__((ext_vector_type(16)));
typedef __bf16 bf16x8 __attribute__((ext_vector_type(8)));

#define KC 8
#define K2L 2304  // 256*9

__device__ __forceinline__ u16 f2bf_rne(float f) {
  unsigned u = __float_as_uint(f);
  u += 0x7FFFu + ((u >> 16) & 1u);
  return (u16)(u >> 16);
}
__device__ __forceinline__ float bf2f(u16 h) {
  return __uint_as_float(((unsigned)h) << 16);
}

// async global->LDS, 16B/lane; LDS dest is the WAVE-UNIFORM base (HW adds lane*16)
__device__ __forceinline__ void gload16(const u16* g, u16* l) {
  __builtin_amdgcn_global_load_lds(
      (const __attribute__((address_space(1))) unsigned*)g,
      (__attribute__((address_space(3))) unsigned*)l, 16, 0, 0);
}

template <int N>
__device__ __forceinline__ void vmwait() {
  if constexpr (N == 0)       asm volatile("s_waitcnt vmcnt(0)" ::: "memory");
  else if constexpr (N == 32) asm volatile("s_waitcnt vmcnt(32)" ::: "memory");
  else static_assert(N == 0, "unsupported vmcnt literal");
}
__device__ __forceinline__ void lgkmwait0() {
  asm volatile("s_waitcnt lgkmcnt(0)" ::: "memory");
}

// ---- merged prep: split x, split W1, build Wc1, Wc2 ----
__device__ __forceinline__ void split4(const float* X, u16* hi, u16* lo, int i) {
  f32x4 v = ((const f32x4*)X)[i];
  u16x4 h, l;
#pragma unroll
  for (int c = 0; c < 4; ++c) {
    u16 hb = f2bf_rne(v[c]);
    h[c] = hb;
    l[c] = f2bf_rne(v[c] - bf2f(hb));
  }
  ((u16x4*)hi)[i] = h;
  ((u16x4*)lo)[i] = l;
}
__device__ __forceinline__ void wc_one(const float* coef, const float* sb, const float* sp,
                                       const float* mask, u16* W, int N, int idx) {
  int o = idx / K2L;
  int r = idx - o * K2L;
  int i = r / 9;
  int c = r - i * 9;
  int io = i * N + o;
  float m = mask[io];
  float v = (c == 0) ? m * sb[io] : m * sp[io] * coef[(size_t)io * KC + (c - 1)];
  W[idx] = f2bf_rne(v);
}

__global__ void prep_kernel(const float* __restrict__ x, const float* __restrict__ W1,
                            const float* __restrict__ coef1, const float* __restrict__ sb1,
                            const float* __restrict__ sp1, const float* __restrict__ mask1,
                            const float* __restrict__ coef2, const float* __restrict__ sb2,
                            const float* __restrict__ sp2, const float* __restrict__ mask2,
                            u16* __restrict__ xs_hi, u16* __restrict__ xs_lo,
                            u16* __restrict__ w1_hi, u16* __restrict__ w1_lo,
                            u16* __restrict__ wc1, u16* __restrict__ wc2) {
  const int b = blockIdx.x, tid = threadIdx.x;
  if (b < 4096) {
    split4(x, xs_hi, xs_lo, b * 256 + tid);
  } else if (b < 4096 + 256) {
    split4(W1, w1_hi, w1_lo, (b - 4096) * 256 + tid);
  } else if (b < 4096 + 256 + 2304) {
    wc_one(coef1, sb1, sp1, mask1, wc1, 256, (b - 4352) * 256 + tid);
  } else {
    wc_one(coef2, sb2, sp2, mask2, wc2, 128, (b - 6656) * 256 + tid);
  }
}

// ---- spline tables + divide-free expand ----
struct Spl {
  float g[12];
  float d1[11], d2[10], d3[9];
};
__device__ __forceinline__ void spl_init(const float* __restrict__ grid, Spl& sp) {
#pragma unroll
  for (int j = 0; j < 12; ++j) sp.g[j] = grid[j];
#pragma unroll
  for (int j = 0; j < 11; ++j) sp.d1[j] = 1.0f / (sp.g[j + 1] - sp.g[j]);
#pragma unroll
  for (int j = 0; j < 10; ++j) sp.d2[j] = 1.0f / (sp.g[j + 2] - sp.g[j]);
#pragma unroll
  for (int j = 0; j < 9; ++j) sp.d3[j] = 1.0f / (sp.g[j + 3] - sp.g[j]);
}
__device__ __forceinline__ void expand_one(float v, const Spl& sp, u16* dst) {
  float Bv[11];
#pragma unroll
  for (int j = 0; j < 11; ++j) Bv[j] = (v >= sp.g[j] && v < sp.g[j + 1]) ? 1.0f : 0.0f;
#pragma unroll
  for (int j = 0; j < 10; ++j)
    Bv[j] = (v - sp.g[j]) * sp.d1[j] * Bv[j] + (sp.g[j + 2] - v) * sp.d1[j + 1] * Bv[j + 1];
#pragma unroll
  for (int j = 0; j < 9; ++j)
    Bv[j] = (v - sp.g[j]) * sp.d2[j] * Bv[j] + (sp.g[j + 3] - v) * sp.d2[j + 1] * Bv[j + 1];
#pragma unroll
  for (int j = 0; j < 8; ++j)
    Bv[j] = (v - sp.g[j]) * sp.d3[j] * Bv[j] + (sp.g[j + 4] - v) * sp.d3[j + 1] * Bv[j + 1];
  dst[0] = f2bf_rne(v / (1.0f + __expf(-v)));  // silu
#pragma unroll
  for (int k = 0; k < 8; ++k) dst[1 + k] = f2bf_rne(Bv[k]);
}

// ---- 1-wave MFMA GEMM: block-tile 64x64 owned by ONE wave (no barriers) ----
// C[M,N] = A[M,K']@B[N,K']^T.  BK=128, 2-buf, depth-1 prefetch, counted vmcnt.
// Fragment reuse 2x2 (wave-tile 64x64, 32x32x16 mfma): FLOP/LDS-byte = 32.
// Staging: linear LDS dest (gload_lds) + inverse-swizzled global SOURCE +
// swizzled LDS READ; 16 slots/row XOR row&15 -> 2-way per 16-lane phase (free).
// NREG==3: K'=3*K regions hh/hl/lh (split-precision bf16x3, K=1024).
template <int NREG, bool EXPAND>
__global__ __launch_bounds__(64) void gemm1w(
    const u16* __restrict__ A0, const u16* __restrict__ A1,
    const u16* __restrict__ B0, const u16* __restrict__ B1,
    const float* __restrict__ bias, const float* __restrict__ grid,
    void* __restrict__ outv, int M, int N, int K, int nsteps) {
  constexpr int ASZ = 64 * 128;        // u16 per A (or B) tile
  constexpr int BUF_U16 = 2 * ASZ;     // A+B = 32 KB
  constexpr int STAGE_B = 2 * BUF_U16 * 2;                // 64 KB
  constexpr int EXP_B = EXPAND ? 64 * 64 * 9 * 2 : 0;     // 72 KB
  constexpr int SMEM = (STAGE_B > EXP_B) ? STAGE_B : EXP_B;
  __shared__ __align__(16) char smraw[SMEM];
  u16* smu = (u16*)smraw;

  const int tid = threadIdx.x;  // 0..63, one wave

  // XCD-aware swizzle (grids are multiples of 8)
  const int nb = N >> 6;
  const int nwg = (M >> 6) * nb;
  const int bid = blockIdx.x;
  const int swz = (bid & 7) * (nwg >> 3) + (bid >> 3);
  const int tm = (swz / nb) << 6;
  const int tn = (swz % nb) << 6;

  const u16* pA0 = A0 + (size_t)tm * K;
  const u16* pB0 = B0 + (size_t)tn * K;
  const u16* pA1 = (NREG == 3) ? A1 + (size_t)tm * K : nullptr;
  const u16* pB1 = (NREG == 3) ? B1 + (size_t)tn * K : nullptr;

  // chunk c (0..1023): row=c>>4, slot=c&15; slot sources k-group slot^(row&15).
  // A and B have identical geometry -> one offset table.
  int src[16];
#pragma unroll
  for (int c = 0; c < 16; ++c) {
    int cc = tid + c * 64;
    int r = cc >> 4, sl = cc & 15;
    src[c] = r * K + (((sl ^ (r & 15)) & 15) << 3);  // u16 units
  }

  const int lr = tid & 31;
  const int khf = tid >> 5;

  // swizzled LDS read offsets (u16): row*128 + ((ks*2+khf)^(row&15))*8
  int offA[2][8], offB[2][8];
#pragma unroll
  for (int mb = 0; mb < 2; ++mb) {
    int row = mb * 32 + lr;
#pragma unroll
    for (int ks = 0; ks < 8; ++ks)
      offA[mb][ks] = row * 128 + ((((ks * 2 + khf) ^ (row & 15)) & 15) << 3);
  }
#pragma unroll
  for (int nb2 = 0; nb2 < 2; ++nb2) {
    int row = nb2 * 32 + lr;
#pragma unroll
    for (int ks = 0; ks < 8; ++ks)
      offB[nb2][ks] = row * 128 + ((((ks * 2 + khf) ^ (row & 15)) & 15) << 3);
  }

  auto stage = [&](int buf, int step) {
    int kk;
    const u16 *Ab, *Bb;
    if constexpr (NREG == 3) {
      int reg = step >> 3;  // K=1024 -> 8 BK-128 steps per region
      kk = (step & 7) << 7;
      Ab = (reg == 2) ? pA1 : pA0;
      Bb = (reg == 1) ? pB1 : pB0;
    } else {
      kk = step << 7;
      Ab = pA0;
      Bb = pB0;
    }
    u16* sb = smu + buf * BUF_U16;
#pragma unroll
    for (int c = 0; c < 16; ++c) gload16(Ab + src[c] + kk, sb + c * 512);
#pragma unroll
    for (int c = 0; c < 16; ++c) gload16(Bb + src[c] + kk, sb + ASZ + c * 512);
  };

  f32x16 acc[2][2] = {};
  stage(0, 0);
  for (int i = 0; i < nsteps; ++i) {
    if (i + 1 < nsteps) {
      stage((i + 1) & 1, i + 1);  // 32 loads in flight for next
      vmwait<32>();               // my 32 loads for buf[i&1] landed
    } else {
      vmwait<0>();
    }
    __builtin_amdgcn_sched_barrier(0);

    const u16* sb = smu + (i & 1) * BUF_U16;
    bf16x8 af[2][8], bfr[2][8];
#pragma unroll
    for (int mb = 0; mb < 2; ++mb)
#pragma unroll
      for (int ks = 0; ks < 8; ++ks) af[mb][ks] = *(const bf16x8*)(sb + offA[mb][ks]);
#pragma unroll
    for (int nb2 = 0; nb2 < 2; ++nb2)
#pragma unroll
      for (int ks = 0; ks < 8; ++ks) bfr[nb2][ks] = *(const bf16x8*)(sb + ASZ + offB[nb2][ks]);

#pragma unroll
    for (int ks = 0; ks < 8; ++ks)
#pragma unroll
      for (int mb = 0; mb < 2; ++mb)
#pragma unroll
        for (int nb2 = 0; nb2 < 2; ++nb2)
          acc[mb][nb2] = __builtin_amdgcn_mfma_f32_32x32x16_bf16(af[mb][ks], bfr[nb2][ks],
                                                                 acc[mb][nb2], 0, 0, 0);
    // all my ds_reads consumed before next stage() overwrites the other buffer
    lgkmwait0();
    __builtin_amdgcn_sched_barrier(0);
  }

  // C/D layout (m74/m101): col = lane&31, row = (r&3) + 8*(r>>2) + 4*(lane>>5)
  const int rbase = 4 * khf;
  if constexpr (EXPAND) {
    Spl sp;
    spl_init(grid, sp);
    __syncthreads();  // 1-wave: cheap; fences LDS reuse
    u16* Fl = smu;
#pragma unroll
    for (int mb = 0; mb < 2; ++mb)
#pragma unroll
      for (int nb2 = 0; nb2 < 2; ++nb2) {
        int col = nb2 * 32 + lr;
        float bv = bias ? bias[tn + col] : 0.0f;
        const f32x16 a = acc[mb][nb2];
#pragma unroll
        for (int r = 0; r < 16; ++r) {
          int row = mb * 32 + rbase + (r & 3) + 8 * (r >> 2);
          expand_one(a[r] + bv, sp, Fl + (size_t)row * (64 * 9) + col * 9);
        }
      }
    __syncthreads();
    // coalesced copy-out: 64 x 576 bf16 in 16B chunks
    u16* Fout = (u16*)outv;
    constexpr int RB = 64 * 9 / 8;  // 72 chunks/row
    constexpr int CH = 64 * RB;
    const size_t fstride = (size_t)N * 9;
    for (int ch = tid; ch < CH; ch += 64) {
      int r = ch / RB, o = ch - r * RB;
      *(u16x8*)(Fout + (size_t)(tm + r) * fstride + (size_t)tn * 9 + o * 8) =
          *(const u16x8*)(Fl + (size_t)ch * 8);
    }
  } else {
    float* Cp = (float*)outv;
#pragma unroll
    for (int mb = 0; mb < 2; ++mb)
#pragma unroll
      for (int nb2 = 0; nb2 < 2; ++nb2) {
        const f32x16 a = acc[mb][nb2];
        const int cbase = tn + nb2 * 32 + lr;
#pragma unroll
        for (int r = 0; r < 16; ++r) {
          int row = tm + mb * 32 + rbase + (r & 3) + 8 * (r >> 2);
          Cp[(size_t)row * N + cbase] = a[r];
        }
      }
  }
}

extern "C" void kernel_launch(void* const* d_in, const int* in_sizes, int n_in,
                              void* d_out, int out_size, void* d_ws, size_t ws_size,
                              hipStream_t stream) {
  (void)in_sizes; (void)n_in; (void)out_size; (void)ws_size;
  const float* x     = (const float*)d_in[0];   // 4096x1024
  const float* W1    = (const float*)d_in[1];   // 256x1024
  const float* b1    = (const float*)d_in[2];   // 256
  const float* grid1 = (const float*)d_in[3];   // 256x12 (rows identical)
  const float* coef1 = (const float*)d_in[4];   // 256x256x8
  const float* sb1   = (const float*)d_in[5];
  const float* sp1   = (const float*)d_in[6];
  const float* mask1 = (const float*)d_in[7];
  const float* grid2 = (const float*)d_in[8];
  const float* coef2 = (const float*)d_in[9];   // 256x128x8
  const float* sb2   = (const float*)d_in[10];
  const float* sp2   = (const float*)d_in[11];
  const float* mask2 = (const float*)d_in[12];
  float* outp = (float*)d_out;

  char* ws = (char*)d_ws;
  size_t off = 0;
  auto alloc = [&](size_t bytes) {
    char* p = ws + off;
    off += (bytes + 255) & ~(size_t)255;
    return (void*)p;
  };
  u16* xs_hi  = (u16*)alloc((size_t)4096 * 1024 * 2);
  u16* xs_lo  = (u16*)alloc((size_t)4096 * 1024 * 2);
  u16* w1_hi  = (u16*)alloc((size_t)256 * 1024 * 2);
  u16* w1_lo  = (u16*)alloc((size_t)256 * 1024 * 2);
  u16* wc1    = (u16*)alloc((size_t)256 * K2L * 2);
  u16* wc2    = (u16*)alloc((size_t)128 * K2L * 2);
  u16* F1     = (u16*)alloc((size_t)4096 * K2L * 2);
  u16* F2     = (u16*)alloc((size_t)4096 * K2L * 2);

  // merged prep
  prep_kernel<<<7808, 256, 0, stream>>>(x, W1, coef1, sb1, sp1, mask1,
                                        coef2, sb2, sp2, mask2,
                                        xs_hi, xs_lo, w1_hi, w1_lo, wc1, wc2);

  // L1: F1 = expand(x @ W1^T + b1); bf16x3 as K'=3072; 24 steps; 256 blocks x 1 wave
  gemm1w<3, true><<<256, 64, 0, stream>>>(
      xs_hi, xs_lo, w1_hi, w1_lo, b1, grid1, F1, 4096, 256, 1024, 24);

  // L2: F2 = expand(F1 @ Wc1^T); K=2304; 18 steps; 256 blocks x 1 wave
  gemm1w<1, true><<<256, 64, 0, stream>>>(
      F1, nullptr, wc1, nullptr, nullptr, grid2, F2, 4096, 256, 2304, 18);

  // L3: out = F2 @ Wc2^T; K=2304, N=128; 18 steps; 128 blocks x 1 wave
  gemm1w<1, false><<<128, 64, 0, stream>>>(
      F2, nullptr, wc2, nullptr, nullptr, nullptr, outp, 4096, 128, 2304, 18);
}

// Round 10
// 97.373 us; speedup vs baseline: 1.8913x; 1.5481x over previous
//
#include <hip/hip_runtime.h>
#include <math.h>

typedef unsigned short u16;
typedef u16 u16x4 __attribute__((ext_vector_type(4)));
typedef u16 u16x8 __attribute__((ext_vector_type(8)));
typedef float f32x4 __attribute__((ext_vector_type(4)));
typedef float f32x16 __attribute__((ext_vector_type(16)));
typedef __bf16 bf16x8 __attribute__((ext_vector_type(8)));

#define KC 8
#define K2L 2304  // 256*9

__device__ __forceinline__ u16 f2bf_rne(float f) {
  unsigned u = __float_as_uint(f);
  u += 0x7FFFu + ((u >> 16) & 1u);
  return (u16)(u >> 16);
}
__device__ __forceinline__ float bf2f(u16 h) {
  return __uint_as_float(((unsigned)h) << 16);
}

// async global->LDS, 16B/lane; LDS dest is the WAVE-UNIFORM base (HW adds lane*16)
__device__ __forceinline__ void gload16(const u16* g, u16* l) {
  __builtin_amdgcn_global_load_lds(
      (const __attribute__((address_space(1))) unsigned*)g,
      (__attribute__((address_space(3))) unsigned*)l, 16, 0, 0);
}

template <int N>
__device__ __forceinline__ void vmwait() {
  if constexpr (N == 0)      asm volatile("s_waitcnt vmcnt(0)" ::: "memory");
  else if constexpr (N == 4) asm volatile("s_waitcnt vmcnt(4)" ::: "memory");
  else static_assert(N == 0, "unsupported vmcnt literal");
}

// ---- merged prep: split x, split W1, build Wc1, Wc2 ----
__device__ __forceinline__ void split4(const float* X, u16* hi, u16* lo, int i) {
  f32x4 v = ((const f32x4*)X)[i];
  u16x4 h, l;
#pragma unroll
  for (int c = 0; c < 4; ++c) {
    u16 hb = f2bf_rne(v[c]);
    h[c] = hb;
    l[c] = f2bf_rne(v[c] - bf2f(hb));
  }
  ((u16x4*)hi)[i] = h;
  ((u16x4*)lo)[i] = l;
}
__device__ __forceinline__ void wc_one(const float* coef, const float* sb, const float* sp,
                                       const float* mask, u16* W, int N, int idx) {
  int o = idx / K2L;
  int r = idx - o * K2L;
  int i = r / 9;
  int c = r - i * 9;
  int io = i * N + o;
  float m = mask[io];
  float v = (c == 0) ? m * sb[io] : m * sp[io] * coef[(size_t)io * KC + (c - 1)];
  W[idx] = f2bf_rne(v);
}

__global__ void prep_kernel(const float* __restrict__ x, const float* __restrict__ W1,
                            const float* __restrict__ coef1, const float* __restrict__ sb1,
                            const float* __restrict__ sp1, const float* __restrict__ mask1,
                            const float* __restrict__ coef2, const float* __restrict__ sb2,
                            const float* __restrict__ sp2, const float* __restrict__ mask2,
                            u16* __restrict__ xs_hi, u16* __restrict__ xs_lo,
                            u16* __restrict__ w1_hi, u16* __restrict__ w1_lo,
                            u16* __restrict__ wc1, u16* __restrict__ wc2) {
  const int b = blockIdx.x, tid = threadIdx.x;
  if (b < 4096) {
    split4(x, xs_hi, xs_lo, b * 256 + tid);
  } else if (b < 4096 + 256) {
    split4(W1, w1_hi, w1_lo, (b - 4096) * 256 + tid);
  } else if (b < 4096 + 256 + 2304) {
    wc_one(coef1, sb1, sp1, mask1, wc1, 256, (b - 4352) * 256 + tid);
  } else {
    wc_one(coef2, sb2, sp2, mask2, wc2, 128, (b - 6656) * 256 + tid);
  }
}

// ---- spline tables + divide-free expand ----
struct Spl {
  float g[12];
  float d1[11], d2[10], d3[9];
};
__device__ __forceinline__ void spl_init(const float* __restrict__ grid, Spl& sp) {
#pragma unroll
  for (int j = 0; j < 12; ++j) sp.g[j] = grid[j];
#pragma unroll
  for (int j = 0; j < 11; ++j) sp.d1[j] = 1.0f / (sp.g[j + 1] - sp.g[j]);
#pragma unroll
  for (int j = 0; j < 10; ++j) sp.d2[j] = 1.0f / (sp.g[j + 2] - sp.g[j]);
#pragma unroll
  for (int j = 0; j < 9; ++j) sp.d3[j] = 1.0f / (sp.g[j + 3] - sp.g[j]);
}
__device__ __forceinline__ void expand_one(float v, const Spl& sp, u16* dst) {
  float Bv[11];
#pragma unroll
  for (int j = 0; j < 11; ++j) Bv[j] = (v >= sp.g[j] && v < sp.g[j + 1]) ? 1.0f : 0.0f;
#pragma unroll
  for (int j = 0; j < 10; ++j)
    Bv[j] = (v - sp.g[j]) * sp.d1[j] * Bv[j] + (sp.g[j + 2] - v) * sp.d1[j + 1] * Bv[j + 1];
#pragma unroll
  for (int j = 0; j < 9; ++j)
    Bv[j] = (v - sp.g[j]) * sp.d2[j] * Bv[j] + (sp.g[j + 3] - v) * sp.d2[j + 1] * Bv[j + 1];
#pragma unroll
  for (int j = 0; j < 8; ++j)
    Bv[j] = (v - sp.g[j]) * sp.d3[j] * Bv[j] + (sp.g[j + 4] - v) * sp.d3[j + 1] * Bv[j + 1];
  dst[0] = f2bf_rne(v / (1.0f + __expf(-v)));  // silu
#pragma unroll
  for (int k = 0; k < 8; ++k) dst[1 + k] = f2bf_rne(Bv[k]);
}

// ---- occupancy-tuned MFMA GEMM: BM=BN=64, 4 waves (2x2), wave-tile 32x32,
// BK=64, 3-buf ring (48 KB LDS -> 3 blocks/CU = 12 waves/CU), depth-2 prefetch
// with counted vmcnt, ONE s_barrier/step.
// Per-step order: vmwait(own loads) -> barrier -> stage(i+2) -> ds_read -> MFMA.
//   3-buf safety: stage at iter i writes buf (i+2)%3 == (i-1)%3, whose readers
//   (iter i-1) consumed their data before reaching barrier#i; stage is after
//   barrier#i -> race-free. All waves verified buf-i loads pre-barrier.
// NREG==3: K'=3*K regions hh/hl/lh (split-precision bf16x3, K=1024).
// EXPAND: bias+spline epilogue -> bf16 F[M][N*9] via two 32-row LDS half-tiles.
template <int NREG, bool EXPAND>
__global__ __launch_bounds__(256) void gemm3b(
    const u16* __restrict__ A0, const u16* __restrict__ A1,
    const u16* __restrict__ B0, const u16* __restrict__ B1,
    const float* __restrict__ bias, const float* __restrict__ grid,
    void* __restrict__ outv, int M, int N, int K, int nsteps) {
  constexpr int ASZ = 64 * 64;        // u16 per A (or B) tile (8 KB)
  constexpr int BUF_U16 = 2 * ASZ;    // A+B = 16 KB
  __shared__ __align__(16) u16 smu[3 * BUF_U16];  // 48 KB -> 3 blocks/CU

  const int tid = threadIdx.x;
  const int lane = tid & 63;
  const int wid = tid >> 6;

  // XCD-aware swizzle (grid sizes are multiples of 8)
  const int nb = N >> 6;
  const int nwg = (M >> 6) * nb;
  const int bid = blockIdx.x;
  const int swz = (bid & 7) * (nwg >> 3) + (bid >> 3);
  const int tm = (swz / nb) << 6;
  const int tn = (swz % nb) << 6;

  const u16* pA0 = A0 + (size_t)tm * K;
  const u16* pB0 = B0 + (size_t)tn * K;
  const u16* pA1 = (NREG == 3) ? A1 + (size_t)tm * K : nullptr;
  const u16* pB1 = (NREG == 3) ? B1 + (size_t)tn * K : nullptr;

  // chunk c (0..511): row=c>>3, slot=c&7; slot sources k-group slot^(row&7)
  // (inverse-swizzled SOURCE + linear LDS dest + swizzled READ)
  auto srcOff = [&](int c) -> int {
    int r = c >> 3, sl = c & 7;
    return r * K + (((sl ^ (r & 7)) & 7) << 3);  // u16 units
  };
  const int s0 = srcOff(tid);
  const int s1 = srcOff(tid + 256);

  const int wm = (wid >> 1) * 32;
  const int wn = (wid & 1) * 32;
  const int lr = lane & 31;
  const int khf = lane >> 5;

  // swizzled LDS read offsets (u16): row*64 + (((2ks+khf)^(row&7))&7)*8
  int offA[4], offB[4];
#pragma unroll
  for (int ks = 0; ks < 4; ++ks) {
    int rowA = wm + lr;
    int rowB = wn + lr;
    offA[ks] = rowA * 64 + ((((2 * ks + khf) ^ (rowA & 7)) & 7) << 3);
    offB[ks] = rowB * 64 + ((((2 * ks + khf) ^ (rowB & 7)) & 7) << 3);
  }

  auto stage = [&](int buf, int step) {
    int kk;
    const u16 *Ab, *Bb;
    if constexpr (NREG == 3) {
      int reg = step >> 4;  // K=1024 -> 16 BK-64 steps per region
      kk = (step & 15) << 6;
      Ab = (reg == 2) ? pA1 : pA0;
      Bb = (reg == 1) ? pB1 : pB0;
    } else {
      kk = step << 6;
      Ab = pA0;
      Bb = pB0;
    }
    u16* sb = smu + buf * BUF_U16;
    gload16(Ab + s0 + kk, sb + wid * 512);
    gload16(Ab + s1 + kk, sb + 2048 + wid * 512);
    gload16(Bb + s0 + kk, sb + ASZ + wid * 512);
    gload16(Bb + s1 + kk, sb + ASZ + 2048 + wid * 512);
  };

  f32x16 acc0[2] = {}, acc1[2] = {};  // [mb]; ks-parity split for MFMA ILP
  stage(0, 0);
  stage(1, 1);
  int b3 = 2;  // (i+2)%3 tracker
  for (int i = 0; i < nsteps; ++i) {
    if (i + 1 < nsteps) vmwait<4>();  // my loads for buf i landed (next stage still in flight)
    else vmwait<0>();
    __builtin_amdgcn_sched_barrier(0);
    __builtin_amdgcn_s_barrier();  // all waves' buf-i loads landed; prior readers done
    __builtin_amdgcn_sched_barrier(0);
    if (i + 2 < nsteps) stage(b3, i + 2);

    const u16* sb = smu + (i - (i / 3) * 3) * BUF_U16;
    bf16x8 af[2][4], bfr[2][4];
#pragma unroll
    for (int mb = 0; mb < 2; ++mb)
#pragma unroll
      for (int ks = 0; ks < 4; ++ks)
        af[mb][ks] = *(const bf16x8*)(sb + mb * 32 * 64 + offA[ks]);
#pragma unroll
    for (int nb2 = 0; nb2 < 2; ++nb2)
#pragma unroll
      for (int ks = 0; ks < 4; ++ks)
        bfr[nb2][ks] = *(const bf16x8*)(sb + ASZ + nb2 * 32 * 64 + offB[ks]);

    // wave-tile 32x32: mb selects A row-block; this wave's col-block fixed (wn)
    // NOTE: acc[mb] uses A row-block mb vs this wave's B cols; af from wm+... 
#pragma unroll
    for (int ks = 0; ks < 4; ++ks) {
      f32x16& a0 = (ks & 1) ? acc1[0] : acc0[0];
      a0 = __builtin_amdgcn_mfma_f32_32x32x16_bf16(af[0][ks], bfr[0][ks], a0, 0, 0, 0);
    }
#pragma unroll
    for (int ks = 0; ks < 4; ++ks) {
      f32x16& a1 = (ks & 1) ? acc1[1] : acc0[1];
      a1 = __builtin_amdgcn_mfma_f32_32x32x16_bf16(af[1][ks], bfr[1][ks], a1, 0, 0, 0);
    }
    b3 = (b3 == 2) ? 0 : b3 + 1;
  }
  // acc[q] = quadrant q of this wave's 32x32 tile pair:
  // q=0: rows wm..wm+32 x cols wn..wn+32 (af[0]*bfr[0]); q=1: rows wm (same) ...
  f32x16 accv[2];
  accv[0] = acc0[0] + acc1[0];
  accv[1] = acc0[1] + acc1[1];
  // Layout note: wave (wm,wn) computed quadrant (wm,wn) with af[0]/bfr[0]
  // (rows wm+lr? no: af[mb] read rows mb*32 + ... of the A tile).
  // af[mb] covers A rows mb*32+lr; bfr[nb2] covers B rows nb2*32+lr.
  // accv[0] = A-rows[0..32) x B-cols[0..32); accv[1] = A-rows[32..64) x B-cols[32..64).
  // Each wave thus owns DIAGONAL quadrants (0,0) and (1,1) shifted by (wm,wn)?
  // -> wm/wn already baked into off tables; af[0] rows = wm+lr, af[1] rows = wm+32+lr
  //    (mb*32*64 byte offset adds 32 rows), bfr likewise from wn.
  // So accv[0] -> rows tm+wm+.., cols tn+wn+..; accv[1] -> rows tm+wm+32.., cols tn+wn+32..
  // Valid only when wm+32<=... wm in {0,32}: wm+32+lr can reach row 95?? GUARD:
  // wm*?? -- offA built from row=wm+lr; adding mb*32*64 shifts by 32 rows: wm=32,mb=1 -> row 64+lr OUT OF TILE.
  // Fix: waves each own full 32x32 at (wm,wn) only; mb loop must use mb==0 only when
  // computed offsets already include wm. Use single quadrant per wave: ignore accv[1]/af[1].
  // (See epilogue: only accv[0] is stored.)

  const int rbase = 4 * khf;
  if constexpr (EXPAND) {
    Spl sp;
    spl_init(grid, sp);
    u16* Fl = smu;
    // two half-tiles of 32 rows each; this wave's rows land in half (wm>>5)
    const int myhalf = wm >> 5;
#pragma unroll
    for (int half = 0; half < 2; ++half) {
      __syncthreads();
      if (half == myhalf) {
        int col = wn + lr;
        float bv = bias ? bias[tn + col] : 0.0f;
        const f32x16 a = accv[0];
#pragma unroll
        for (int r = 0; r < 16; ++r) {
          int rowl = rbase + (r & 3) + 8 * (r >> 2);  // 0..31 within half
          expand_one(a[r] + bv, sp, Fl + (size_t)rowl * (64 * 9) + col * 9);
        }
      }
      __syncthreads();
      u16* Fout = (u16*)outv;
      const size_t fstride = (size_t)N * 9;
      for (int ch = tid; ch < 2304; ch += 256) {  // 32 rows x 72 16B-chunks
        int rr = ch / 72, o = ch - rr * 72;
        *(u16x8*)(Fout + (size_t)(tm + half * 32 + rr) * fstride + (size_t)tn * 9 + o * 8) =
            *(const u16x8*)(Fl + (size_t)ch * 8);
      }
    }
  } else {
    float* Cp = (float*)outv;
    const f32x16 a = accv[0];
    const int cbase = tn + wn + lr;
#pragma unroll
    for (int r = 0; r < 16; ++r) {
      int row = tm + wm + rbase + (r & 3) + 8 * (r >> 2);
      Cp[(size_t)row * N + cbase] = a[r];
    }
  }
}

extern "C" void kernel_launch(void* const* d_in, const int* in_sizes, int n_in,
                              void* d_out, int out_size, void* d_ws, size_t ws_size,
                              hipStream_t stream) {
  (void)in_sizes; (void)n_in; (void)out_size; (void)ws_size;
  const float* x     = (const float*)d_in[0];   // 4096x1024
  const float* W1    = (const float*)d_in[1];   // 256x1024
  const float* b1    = (const float*)d_in[2];   // 256
  const float* grid1 = (const float*)d_in[3];   // 256x12 (rows identical)
  const float* coef1 = (const float*)d_in[4];   // 256x256x8
  const float* sb1   = (const float*)d_in[5];
  const float* sp1   = (const float*)d_in[6];
  const float* mask1 = (const float*)d_in[7];
  const float* grid2 = (const float*)d_in[8];
  const float* coef2 = (const float*)d_in[9];   // 256x128x8
  const float* sb2   = (const float*)d_in[10];
  const float* sp2   = (const float*)d_in[11];
  const float* mask2 = (const float*)d_in[12];
  float* outp = (float*)d_out;

  char* ws = (char*)d_ws;
  size_t off = 0;
  auto alloc = [&](size_t bytes) {
    char* p = ws + off;
    off += (bytes + 255) & ~(size_t)255;
    return (void*)p;
  };
  u16* xs_hi  = (u16*)alloc((size_t)4096 * 1024 * 2);
  u16* xs_lo  = (u16*)alloc((size_t)4096 * 1024 * 2);
  u16* w1_hi  = (u16*)alloc((size_t)256 * 1024 * 2);
  u16* w1_lo  = (u16*)alloc((size_t)256 * 1024 * 2);
  u16* wc1    = (u16*)alloc((size_t)256 * K2L * 2);
  u16* wc2    = (u16*)alloc((size_t)128 * K2L * 2);
  u16* F1     = (u16*)alloc((size_t)4096 * K2L * 2);
  u16* F2     = (u16*)alloc((size_t)4096 * K2L * 2);

  // merged prep
  prep_kernel<<<7808, 256, 0, stream>>>(x, W1, coef1, sb1, sp1, mask1,
                                        coef2, sb2, sp2, mask2,
                                        xs_hi, xs_lo, w1_hi, w1_lo, wc1, wc2);

  // L1: F1 = expand(x @ W1^T + b1); bf16x3 as K'=3072; BK=64 -> 48 steps; 256 blocks
  gemm3b<3, true><<<256, 256, 0, stream>>>(
      xs_hi, xs_lo, w1_hi, w1_lo, b1, grid1, F1, 4096, 256, 1024, 48);

  // L2: F2 = expand(F1 @ Wc1^T); K=2304 -> 36 steps; 256 blocks
  gemm3b<1, true><<<256, 256, 0, stream>>>(
      F1, nullptr, wc1, nullptr, nullptr, grid2, F2, 4096, 256, 2304, 36);

  // L3: out = F2 @ Wc2^T; K=2304, N=128 -> 36 steps; 128 blocks
  gemm3b<1, false><<<128, 256, 0, stream>>>(
      F2, nullptr, wc2, nullptr, nullptr, nullptr, outp, 4096, 128, 2304, 36);
}

// Round 11
// 68.815 us; speedup vs baseline: 2.6762x; 1.4150x over previous
//
#include <hip/hip_runtime.h>
#include <math.h>

typedef unsigned short u16;
typedef u16 u16x4 __attribute__((ext_vector_type(4)));
typedef u16 u16x8 __attribute__((ext_vector_type(8)));
typedef float f32x4 __attribute__((ext_vector_type(4)));
typedef float f32x16 __attribute__((ext_vector_type(16)));
typedef __bf16 bf16x8 __attribute__((ext_vector_type(8)));

#define KC 8
#define K2L 2304  // 256*9

__device__ __forceinline__ u16 f2bf_rne(float f) {
  unsigned u = __float_as_uint(f);
  u += 0x7FFFu + ((u >> 16) & 1u);
  return (u16)(u >> 16);
}
__device__ __forceinline__ float bf2f(u16 h) {
  return __uint_as_float(((unsigned)h) << 16);
}

// async global->LDS, 16B/lane; LDS dest is the WAVE-UNIFORM base (HW adds lane*16)
__device__ __forceinline__ void gload16(const u16* g, u16* l) {
  __builtin_amdgcn_global_load_lds(
      (const __attribute__((address_space(1))) unsigned*)g,
      (__attribute__((address_space(3))) unsigned*)l, 16, 0, 0);
}

template <int N>
__device__ __forceinline__ void vmwait() {
  if constexpr (N == 0)      asm volatile("s_waitcnt vmcnt(0)" ::: "memory");
  else if constexpr (N == 4) asm volatile("s_waitcnt vmcnt(4)" ::: "memory");
  else if constexpr (N == 8) asm volatile("s_waitcnt vmcnt(8)" ::: "memory");
  else static_assert(N == 0, "unsupported vmcnt literal");
}

// ---- merged prep: split x, split W1, build Wc1, Wc2 ----
__device__ __forceinline__ void split4(const float* X, u16* hi, u16* lo, int i) {
  f32x4 v = ((const f32x4*)X)[i];
  u16x4 h, l;
#pragma unroll
  for (int c = 0; c < 4; ++c) {
    u16 hb = f2bf_rne(v[c]);
    h[c] = hb;
    l[c] = f2bf_rne(v[c] - bf2f(hb));
  }
  ((u16x4*)hi)[i] = h;
  ((u16x4*)lo)[i] = l;
}
__device__ __forceinline__ void wc_one(const float* coef, const float* sb, const float* sp,
                                       const float* mask, u16* W, int N, int idx) {
  int o = idx / K2L;
  int r = idx - o * K2L;
  int i = r / 9;
  int c = r - i * 9;
  int io = i * N + o;
  float m = mask[io];
  float v = (c == 0) ? m * sb[io] : m * sp[io] * coef[(size_t)io * KC + (c - 1)];
  W[idx] = f2bf_rne(v);
}

__global__ void prep_kernel(const float* __restrict__ x, const float* __restrict__ W1,
                            const float* __restrict__ coef1, const float* __restrict__ sb1,
                            const float* __restrict__ sp1, const float* __restrict__ mask1,
                            const float* __restrict__ coef2, const float* __restrict__ sb2,
                            const float* __restrict__ sp2, const float* __restrict__ mask2,
                            u16* __restrict__ xs_hi, u16* __restrict__ xs_lo,
                            u16* __restrict__ w1_hi, u16* __restrict__ w1_lo,
                            u16* __restrict__ wc1, u16* __restrict__ wc2) {
  const int b = blockIdx.x, tid = threadIdx.x;
  if (b < 4096) {
    split4(x, xs_hi, xs_lo, b * 256 + tid);
  } else if (b < 4096 + 256) {
    split4(W1, w1_hi, w1_lo, (b - 4096) * 256 + tid);
  } else if (b < 4096 + 256 + 2304) {
    wc_one(coef1, sb1, sp1, mask1, wc1, 256, (b - 4352) * 256 + tid);
  } else {
    wc_one(coef2, sb2, sp2, mask2, wc2, 128, (b - 6656) * 256 + tid);
  }
}

// ---- spline tables + divide-free expand ----
struct Spl {
  float g[12];
  float d1[11], d2[10], d3[9];
};
__device__ __forceinline__ void spl_init(const float* __restrict__ grid, Spl& sp) {
#pragma unroll
  for (int j = 0; j < 12; ++j) sp.g[j] = grid[j];
#pragma unroll
  for (int j = 0; j < 11; ++j) sp.d1[j] = 1.0f / (sp.g[j + 1] - sp.g[j]);
#pragma unroll
  for (int j = 0; j < 10; ++j) sp.d2[j] = 1.0f / (sp.g[j + 2] - sp.g[j]);
#pragma unroll
  for (int j = 0; j < 9; ++j) sp.d3[j] = 1.0f / (sp.g[j + 3] - sp.g[j]);
}
__device__ __forceinline__ void expand_one(float v, const Spl& sp, u16* dst) {
  float Bv[11];
#pragma unroll
  for (int j = 0; j < 11; ++j) Bv[j] = (v >= sp.g[j] && v < sp.g[j + 1]) ? 1.0f : 0.0f;
#pragma unroll
  for (int j = 0; j < 10; ++j)
    Bv[j] = (v - sp.g[j]) * sp.d1[j] * Bv[j] + (sp.g[j + 2] - v) * sp.d1[j + 1] * Bv[j + 1];
#pragma unroll
  for (int j = 0; j < 9; ++j)
    Bv[j] = (v - sp.g[j]) * sp.d2[j] * Bv[j] + (sp.g[j + 3] - v) * sp.d2[j + 1] * Bv[j + 1];
#pragma unroll
  for (int j = 0; j < 8; ++j)
    Bv[j] = (v - sp.g[j]) * sp.d3[j] * Bv[j] + (sp.g[j + 4] - v) * sp.d3[j + 1] * Bv[j + 1];
  dst[0] = f2bf_rne(v / (1.0f + __expf(-v)));  // silu
#pragma unroll
  for (int k = 0; k < 8; ++k) dst[1 + k] = f2bf_rne(Bv[k]);
}

// ---- 8-wave MFMA GEMM (R6 pipeline + 2 waves/SIMD) ----
// BM=BN=64, 8 waves: quadrant q=wid&3 -> (wm,wn)=((q>>1)*32,(q&1)*32);
// K-group kg=wid>>2 (slices kg*4..kg*4+3 of the 8 K-16 slices per BK=128 step).
// 4-buf ring, depth-2 prefetch, counted vmcnt, ONE s_barrier/step (R6-proven).
// Epilogue: LDS f32 pair-reduction (kg1 -> kg0), then fused bias+spline expand.
// NREG==3: K'=3*K regions hh/hl/lh (split-precision bf16x3, K=1024).
template <int NREG, bool EXPAND>
__global__ __launch_bounds__(512) void gemm8w(
    const u16* __restrict__ A0, const u16* __restrict__ A1,
    const u16* __restrict__ B0, const u16* __restrict__ B1,
    const float* __restrict__ bias, const float* __restrict__ grid,
    void* __restrict__ outv, int M, int N, int K, int nsteps) {
  constexpr int ASZ = 64 * 128;     // u16 per A (or B) tile (16 KB)
  constexpr int BUF_U16 = 2 * ASZ;  // 32 KB
  __shared__ __align__(16) u16 smu[4 * BUF_U16];  // 128 KB -> 1 block/CU, 16 waves

  const int tid = threadIdx.x;
  const int lane = tid & 63;
  const int wid = tid >> 6;
  const int q = wid & 3;
  const int kg = wid >> 2;

  // XCD-aware swizzle (grid sizes are multiples of 8)
  const int nb = N >> 6;
  const int nwg = (M >> 6) * nb;
  const int bid = blockIdx.x;
  const int swz = (bid & 7) * (nwg >> 3) + (bid >> 3);
  const int tm = (swz / nb) << 6;
  const int tn = (swz % nb) << 6;

  const u16* pA0 = A0 + (size_t)tm * K;
  const u16* pB0 = B0 + (size_t)tn * K;
  const u16* pA1 = (NREG == 3) ? A1 + (size_t)tm * K : nullptr;
  const u16* pB1 = (NREG == 3) ? B1 + (size_t)tn * K : nullptr;

  // staging chunk c (0..1023 per tile): row=c>>4, slot=c&15; slot sources
  // k-group slot^(row&15)  (inverse-swizzled SOURCE + linear dest + swizzled READ)
  auto srcOff = [&](int c) -> int {
    int r = c >> 4, sl = c & 15;
    return r * K + (((sl ^ (r & 15)) & 15) << 3);  // u16 units
  };
  const int s0 = srcOff(tid);
  const int s1 = srcOff(tid + 512);

  const int wm = (q >> 1) * 32;
  const int wn = (q & 1) * 32;
  const int lr = lane & 31;
  const int khf = lane >> 5;

  // swizzled LDS read offsets (u16): row*128 + ((slot^(row&15))&15)*8,
  // slot = slice*2 + khf, slice = kg*4 + s
  int offA[4], offB[4];
#pragma unroll
  for (int s = 0; s < 4; ++s) {
    int slice = kg * 4 + s;
    int rowA = wm + lr;
    int rowB = wn + lr;
    offA[s] = rowA * 128 + ((((slice * 2 + khf) ^ (rowA & 15)) & 15) << 3);
    offB[s] = rowB * 128 + ((((slice * 2 + khf) ^ (rowB & 15)) & 15) << 3);
  }

  auto stage = [&](int buf, int step) {
    int kk;
    const u16 *Ab, *Bb;
    if constexpr (NREG == 3) {
      int reg = step >> 3;  // K=1024 -> 8 BK-128 steps per region
      kk = (step & 7) << 7;
      Ab = (reg == 2) ? pA1 : pA0;
      Bb = (reg == 1) ? pB1 : pB0;
    } else {
      kk = step << 7;
      Ab = pA0;
      Bb = pB0;
    }
    u16* sb = smu + buf * BUF_U16;
    gload16(Ab + s0 + kk, sb + wid * 512);
    gload16(Ab + s1 + kk, sb + 4096 + wid * 512);
    gload16(Bb + s0 + kk, sb + ASZ + wid * 512);
    gload16(Bb + s1 + kk, sb + ASZ + 4096 + wid * 512);
  };

  f32x16 acc0 = {}, acc1 = {};
  stage(0, 0);
  stage(1, 1);
  for (int i = 0; i < nsteps; ++i) {
    if (i + 2 < nsteps) {
      stage((i + 2) & 3, i + 2);
      vmwait<8>();  // my 4 loads for buf[i&3] landed (2 stages in flight)
    } else if (i + 1 < nsteps) {
      vmwait<4>();
    } else {
      vmwait<0>();
    }
    __builtin_amdgcn_sched_barrier(0);
    __builtin_amdgcn_s_barrier();  // all waves' buf-i loads landed;
                                   // also fences reads of buf[(i+2)&3] (iter i-2)
    __builtin_amdgcn_sched_barrier(0);

    const u16* sb = smu + (i & 3) * BUF_U16;
    bf16x8 af[4], bfr[4];
#pragma unroll
    for (int s = 0; s < 4; ++s) {
      af[s] = *(const bf16x8*)(sb + offA[s]);
      bfr[s] = *(const bf16x8*)(sb + ASZ + offB[s]);
    }
#pragma unroll
    for (int s = 0; s < 4; ++s) {
      f32x16& ac = (s & 1) ? acc1 : acc0;  // 2 chains for MFMA ILP
      ac = __builtin_amdgcn_mfma_f32_32x32x16_bf16(af[s], bfr[s], ac, 0, 0, 0);
    }
  }
  f32x16 accv = acc0 + acc1;

  // C/D layout (m74/m101): col = lane&31, row = (r&3) + 8*(r>>2) + 4*(lane>>5)
  const int rbase = 4 * khf;

  // cross-wave K-group reduction via LDS f32 (16 KB in buf0; stage use done)
  float* Fr = (float*)smu;
  __syncthreads();
  if (kg == 1) {
#pragma unroll
    for (int r = 0; r < 16; ++r) {
      int row = wm + rbase + (r & 3) + 8 * (r >> 2);
      Fr[row * 64 + wn + lr] = accv[r];
    }
  }
  __syncthreads();
  if (kg == 0) {
#pragma unroll
    for (int r = 0; r < 16; ++r) {
      int row = wm + rbase + (r & 3) + 8 * (r >> 2);
      accv[r] += Fr[row * 64 + wn + lr];
    }
  }

  if constexpr (EXPAND) {
    Spl sp;
    spl_init(grid, sp);
    __syncthreads();  // Fr reads done before F-tile overwrite
    u16* Fl = smu;
    if (kg == 0) {
      int col = wn + lr;
      float bv = bias ? bias[tn + col] : 0.0f;
#pragma unroll
      for (int r = 0; r < 16; ++r) {
        int row = wm + rbase + (r & 3) + 8 * (r >> 2);
        expand_one(accv[r] + bv, sp, Fl + (size_t)row * (64 * 9) + col * 9);
      }
    }
    __syncthreads();
    // coalesced copy-out: 64 x 576 bf16 in 16B chunks, all 512 threads
    u16* Fout = (u16*)outv;
    const size_t fstride = (size_t)N * 9;
#pragma unroll
    for (int ch = tid; ch < 4608; ch += 512) {  // 64 rows x 72 chunks
      int r = ch / 72, o = ch - r * 72;
      *(u16x8*)(Fout + (size_t)(tm + r) * fstride + (size_t)tn * 9 + o * 8) =
          *(const u16x8*)(Fl + (size_t)ch * 8);
    }
  } else {
    if (kg == 0) {
      float* Cp = (float*)outv;
      const int cbase = tn + wn + lr;
#pragma unroll
      for (int r = 0; r < 16; ++r) {
        int row = tm + wm + rbase + (r & 3) + 8 * (r >> 2);
        Cp[(size_t)row * N + cbase] = accv[r];
      }
    }
  }
}

extern "C" void kernel_launch(void* const* d_in, const int* in_sizes, int n_in,
                              void* d_out, int out_size, void* d_ws, size_t ws_size,
                              hipStream_t stream) {
  (void)in_sizes; (void)n_in; (void)out_size; (void)ws_size;
  const float* x     = (const float*)d_in[0];   // 4096x1024
  const float* W1    = (const float*)d_in[1];   // 256x1024
  const float* b1    = (const float*)d_in[2];   // 256
  const float* grid1 = (const float*)d_in[3];   // 256x12 (rows identical)
  const float* coef1 = (const float*)d_in[4];   // 256x256x8
  const float* sb1   = (const float*)d_in[5];
  const float* sp1   = (const float*)d_in[6];
  const float* mask1 = (const float*)d_in[7];
  const float* grid2 = (const float*)d_in[8];
  const float* coef2 = (const float*)d_in[9];   // 256x128x8
  const float* sb2   = (const float*)d_in[10];
  const float* sp2   = (const float*)d_in[11];
  const float* mask2 = (const float*)d_in[12];
  float* outp = (float*)d_out;

  char* ws = (char*)d_ws;
  size_t off = 0;
  auto alloc = [&](size_t bytes) {
    char* p = ws + off;
    off += (bytes + 255) & ~(size_t)255;
    return (void*)p;
  };
  u16* xs_hi  = (u16*)alloc((size_t)4096 * 1024 * 2);
  u16* xs_lo  = (u16*)alloc((size_t)4096 * 1024 * 2);
  u16* w1_hi  = (u16*)alloc((size_t)256 * 1024 * 2);
  u16* w1_lo  = (u16*)alloc((size_t)256 * 1024 * 2);
  u16* wc1    = (u16*)alloc((size_t)256 * K2L * 2);
  u16* wc2    = (u16*)alloc((size_t)128 * K2L * 2);
  u16* F1     = (u16*)alloc((size_t)4096 * K2L * 2);
  u16* F2     = (u16*)alloc((size_t)4096 * K2L * 2);

  // merged prep
  prep_kernel<<<7808, 256, 0, stream>>>(x, W1, coef1, sb1, sp1, mask1,
                                        coef2, sb2, sp2, mask2,
                                        xs_hi, xs_lo, w1_hi, w1_lo, wc1, wc2);

  // L1: F1 = expand(x @ W1^T + b1); bf16x3 as K'=3072; 24 steps; 256 blocks x 8 waves
  gemm8w<3, true><<<256, 512, 0, stream>>>(
      xs_hi, xs_lo, w1_hi, w1_lo, b1, grid1, F1, 4096, 256, 1024, 24);

  // L2: F2 = expand(F1 @ Wc1^T); K=2304; 18 steps; 256 blocks x 8 waves
  gemm8w<1, true><<<256, 512, 0, stream>>>(
      F1, nullptr, wc1, nullptr, nullptr, grid2, F2, 4096, 256, 2304, 18);

  // L3: out = F2 @ Wc2^T; K=2304, N=128; 18 steps; 128 blocks x 8 waves
  gemm8w<1, false><<<128, 512, 0, stream>>>(
      F2, nullptr, wc2, nullptr, nullptr, nullptr, outp, 4096, 128, 2304, 18);
}